// Round 9
// baseline (676.871 us; speedup 1.0000x reference)
//
#include <hip/hip_runtime.h>
#include <math.h>

#define NN 50000
#define EE 800000
#define NB 196   // ceil(NN/256)

typedef _Float16 half8 __attribute__((ext_vector_type(8)));
typedef _Float16 hv4  __attribute__((ext_vector_type(4)));
typedef _Float16 hv2  __attribute__((ext_vector_type(2)));
typedef float floatx16 __attribute__((ext_vector_type(16)));
typedef float fv4 __attribute__((ext_vector_type(4)));

__device__ __forceinline__ float fexp2(float x) { return __builtin_amdgcn_exp2f(x); }

// DPP row_ror all-reduce within 16-lane rows: rotations by 1,2,4,8.
template<int CTRL>
__device__ __forceinline__ float dppadd(float x) {
    int t = __builtin_amdgcn_update_dpp(0, __float_as_int(x), CTRL, 0xf, 0xf, false);
    return x + __int_as_float(t);
}
__device__ __forceinline__ float red16(float x) {
    x = dppadd<0x121>(x);   // row_ror:1
    x = dppadd<0x122>(x);   // row_ror:2
    x = dppadd<0x124>(x);   // row_ror:4
    x = dppadd<0x128>(x);   // row_ror:8
    return x;
}

// ------------------------------------------------------------------
// Swizzle A (fp32 row-major M x K) into 32x32x16 MFMA A-fragment order.
// Used only for the input x (K=128); later layers fuse this into attn.
// Grid x must cover all tiles the GEMM will read (zero-fills past M).
// ------------------------------------------------------------------
__global__ __launch_bounds__(256) void swizzleA(
    const float* __restrict__ A, _Float16* __restrict__ Asw, int M, int K)
{
    int wave = threadIdx.x >> 6, lane = threadIdx.x & 63;
    int tile = blockIdx.x;
    int kc = blockIdx.y * 4 + wave;
    int KC = K >> 4;
    if (kc >= KC) return;
    int row = tile * 32 + (lane & 31);
    int k0 = kc * 16 + (lane >> 5) * 8;
    float4 v0 = make_float4(0.f, 0.f, 0.f, 0.f);
    float4 v1 = make_float4(0.f, 0.f, 0.f, 0.f);
    if (row < M) {
        const float* p = A + (size_t)row * K + k0;
        v0 = *(const float4*)p;
        v1 = *(const float4*)(p + 4);
    }
    half8 o;
    o[0] = (_Float16)v0.x; o[1] = (_Float16)v0.y;
    o[2] = (_Float16)v0.z; o[3] = (_Float16)v0.w;
    o[4] = (_Float16)v1.x; o[5] = (_Float16)v1.y;
    o[6] = (_Float16)v1.z; o[7] = (_Float16)v1.w;
    *(half8*)(Asw + (((size_t)tile * KC + kc) * 64 + lane) * 8) = o;
}

// ------------------------------------------------------------------
// All weight swizzles + bias concats in ONE dispatch.
// Columns even/odd interleaved per 64-col group: tile 2g = even cols,
// tile 2g+1 = odd cols -> GEMM epilogue packs pairs into 4B stores.
// ------------------------------------------------------------------
__global__ __launch_bounds__(256) void prep_weights(
    const float* __restrict__ s0, const float* __restrict__ s1,
    const float* __restrict__ s2, const float* __restrict__ s3,
    const float* __restrict__ s4, const float* __restrict__ s5,
    const float* __restrict__ s6, const float* __restrict__ s7,
    _Float16* __restrict__ catB0, _Float16* __restrict__ catB1,
    _Float16* __restrict__ catB2,
    const float* __restrict__ bl0, const float* __restrict__ br0,
    const float* __restrict__ pb0, const float* __restrict__ bl1,
    const float* __restrict__ br1, const float* __restrict__ bl2,
    const float* __restrict__ br2, const float* __restrict__ pb2,
    float* __restrict__ cb0, float* __restrict__ cb1, float* __restrict__ cb2)
{
    int b = blockIdx.x;
    if (b >= 184) {
        int t = (b - 184) * 256 + threadIdx.x;   // 0..2047
        if (t < 768) {
            cb0[t] = (t < 256) ? bl0[t] : (t < 512) ? br0[t - 256] : pb0[t - 512];
        } else if (t < 1280) {
            int u = t - 768;
            cb1[u] = (u < 256) ? bl1[u] : br1[u - 256];
        } else if (t < 1856) {
            int u = t - 1280;
            cb2[u] = (u < 256) ? bl2[u] : (u < 512) ? br2[u - 256] : pb2[u - 512];
        }
        return;
    }
    int wave = threadIdx.x >> 6, lane = threadIdx.x & 63;
    int pair = b * 4 + wave;     // 0..735
    const int cum[9] = {0, 64, 128, 192, 320, 448, 576, 704, 736};
    int job = 0;
    while (pair >= cum[job + 1]) ++job;
    const float* srcs[8] = {s0, s1, s2, s3, s4, s5, s6, s7};
    const int KCs[8] = {8, 8, 8, 16, 16, 16, 16, 16};
    const int NCs[8] = {256, 256, 256, 256, 256, 256, 256, 64};
    const int ntb[8] = {0, 8, 16, 0, 8, 0, 8, 16};
    _Float16* dsts[8] = {catB0, catB0, catB0, catB1, catB1, catB2, catB2, catB2};
    int p = pair - cum[job];
    int KC = KCs[job], NC = NCs[job];
    int nt = p / KC, kc = p - nt * KC;
    int n = (nt >> 1) * 64 + ((lane & 31) * 2) + (nt & 1);
    int k0 = kc * 16 + (lane >> 5) * 8;
    const float* B = srcs[job];
    half8 o;
#pragma unroll
    for (int jj = 0; jj < 8; ++jj)
        o[jj] = (_Float16)B[(size_t)(k0 + jj) * NC + n];
    int ntG = ntb[job] + nt;
    *(half8*)(dsts[job] + (((size_t)ntG * KC + kc) * 64 + lane) * 8) = o;
}

// ------------------------------------------------------------------
// MFMA GEMM with LDS-staged B: one 64-col group per block, 256 rows.
// Stage B tiles (2g, 2g+1) into LDS once (one barrier), then a
// barrier-free K-loop: 2 global A-loads + 2 ds_read_b128 + 4 MFMA / kc.
// Epilogue packs (even,odd) col pair into one 4B store.
// ------------------------------------------------------------------
__global__ __launch_bounds__(256) void gemm_mfma(
    const _Float16* __restrict__ Asw, const _Float16* __restrict__ Bsw,
    const float* __restrict__ bias, _Float16* __restrict__ C,
    int M, int K, int NC)
{
    __shared__ _Float16 lb[16384];   // up to 32 KB (KC=16)
    const int wave = threadIdx.x >> 6, lane = threadIdx.x & 63;
    const int KC = K >> 4;
    const int g = blockIdx.y;

    {
        const _Float16* srcB = Bsw + (size_t)(2 * g) * KC * 512;
        int total = 2 * KC * 512;
        for (int t = threadIdx.x * 8; t < total; t += 2048)
            *(half8*)(lb + t) = *(const half8*)(srcB + t);
    }
    __syncthreads();

    const int rt0 = blockIdx.x * 8 + wave * 2;   // 2 row-tiles per wave
    const half8* Ap0 = (const half8*)Asw + (size_t)rt0 * KC * 64 + lane;
    const half8* Ap1 = Ap0 + (size_t)KC * 64;
    const half8* Bl0 = (const half8*)lb + lane;
    const half8* Bl1 = (const half8*)lb + (size_t)KC * 64 + lane;

    floatx16 accE0 = {0.f}, accE1 = {0.f}, accO0 = {0.f}, accO1 = {0.f};

#pragma unroll 4
    for (int kc = 0; kc < KC; ++kc) {
        half8 a0 = Ap0[(size_t)kc * 64];
        half8 a1 = Ap1[(size_t)kc * 64];
        half8 b0 = Bl0[(size_t)kc * 64];
        half8 b1 = Bl1[(size_t)kc * 64];
        accE0 = __builtin_amdgcn_mfma_f32_32x32x16_f16(a0, b0, accE0, 0, 0, 0);
        accE1 = __builtin_amdgcn_mfma_f32_32x32x16_f16(a1, b0, accE1, 0, 0, 0);
        accO0 = __builtin_amdgcn_mfma_f32_32x32x16_f16(a0, b1, accO0, 0, 0, 0);
        accO1 = __builtin_amdgcn_mfma_f32_32x32x16_f16(a1, b1, accO1, 0, 0, 0);
    }

    const int nlane = lane & 31, hs = lane >> 5;
    int colb = g * 64 + nlane * 2;
    float be = bias[colb], bo = bias[colb + 1];
#pragma unroll
    for (int r = 0; r < 16; ++r) {
        int rowin = (r & 3) + 8 * (r >> 2) + 4 * hs;
        int row0 = rt0 * 32 + rowin;
        int row1 = row0 + 32;
        if (row0 < M) {
            hv2 pe;
            pe[0] = (_Float16)(accE0[r] + be);
            pe[1] = (_Float16)(accO0[r] + bo);
            *(hv2*)(C + (size_t)row0 * NC + colb) = pe;
        }
        if (row1 < M) {
            hv2 po;
            po[0] = (_Float16)(accE1[r] + be);
            po[1] = (_Float16)(accO1[r] + bo);
            *(hv2*)(C + (size_t)row1 * NC + colb) = po;
        }
    }
}

// ------------------------------------------------------------------
// CSR build: histogram -> two-level scan -> scatter
// ------------------------------------------------------------------
__global__ __launch_bounds__(256) void hist_kernel(const int* __restrict__ dst,
                                                   int* __restrict__ deg)
{
    int e = blockIdx.x * 256 + threadIdx.x;
    if (e < EE) atomicAdd(&deg[dst[e]], 1);
}

__global__ __launch_bounds__(256) void scan_local(const int* __restrict__ deg,
                                                  int* __restrict__ rowoff,
                                                  int* __restrict__ part)
{
    __shared__ int sd[256];
    int tid = threadIdx.x;
    int i = blockIdx.x * 256 + tid;
    int v = (i < NN) ? deg[i] : 0;
    sd[tid] = v;
    __syncthreads();
    for (int off = 1; off < 256; off <<= 1) {
        int t = (tid >= off) ? sd[tid - off] : 0;
        __syncthreads();
        sd[tid] += t;
        __syncthreads();
    }
    if (i < NN) rowoff[i] = sd[tid] - v;
    if (tid == 255) part[blockIdx.x] = sd[255];
}

__global__ __launch_bounds__(256) void scan_part(int* __restrict__ part,
                                                 int* __restrict__ rowoff)
{
    __shared__ int sd[256];
    int tid = threadIdx.x;
    int v = (tid < NB) ? part[tid] : 0;
    sd[tid] = v;
    __syncthreads();
    for (int off = 1; off < 256; off <<= 1) {
        int t = (tid >= off) ? sd[tid - off] : 0;
        __syncthreads();
        sd[tid] += t;
        __syncthreads();
    }
    if (tid < NB) part[tid] = sd[tid] - v;
    if (tid == 0) rowoff[NN] = EE;
}

__global__ __launch_bounds__(256) void scan_add(int* __restrict__ rowoff,
                                                const int* __restrict__ part,
                                                int* __restrict__ cursor)
{
    int i = blockIdx.x * 256 + threadIdx.x;
    if (i < NN) {
        rowoff[i] += part[blockIdx.x];
        cursor[i] = 0;
    }
}

__global__ __launch_bounds__(256) void scatter_kernel(
    const int* __restrict__ src, const int* __restrict__ dst,
    const float* __restrict__ ea, const int* __restrict__ rowoff,
    int* __restrict__ cursor, int* __restrict__ srcp,
    float4* __restrict__ eap, float* __restrict__ erec)
{
    int e = blockIdx.x * 256 + threadIdx.x;
    if (e < EE) {
        int d = dst[e];
        int pos = rowoff[d] + atomicAdd(&cursor[d], 1);
        srcp[pos] = src[e];
        const float* p = ea + (size_t)e * 5;
        eap[pos] = make_float4(p[0], p[1], p[2], p[3]);
        erec[pos] = 1.0f / fmaxf(p[3], 1e-6f);
    }
}

// ------------------------------------------------------------------
// Fused GATv2 + LayerNorm + residual (+ELU) + A-swizzle for next GEMM.
// One wave per node, edge loop unrolled x4. Compile-time MODE/RSTRIDE.
// MODE 0: concat 256, fp16 resid slice, ELU; writes h (fp32) + Asw
// MODE 1: concat 256, fp32 resid (stride 256), ELU; writes Asw only
// MODE 2: head-mean 64, fp16 resid slice, no ELU; writes outF (64-wide)
// ------------------------------------------------------------------
template<int MODE, int RSTRIDE>
__global__ __launch_bounds__(256) void fused_attn_ln(
    const int* __restrict__ rowoff, const int* __restrict__ srcp,
    const float4* __restrict__ eap, const float* __restrict__ erec,
    const _Float16* __restrict__ xlp,
    const float* __restrict__ We, const float* __restrict__ att,
    const float* __restrict__ temp, const float* __restrict__ bias,
    const float* __restrict__ lnw, const float* __restrict__ lnb,
    const _Float16* __restrict__ residH, const float* __restrict__ residF,
    float* __restrict__ outF, _Float16* __restrict__ aswOut)
{
    int v = __builtin_amdgcn_readfirstlane(blockIdx.x * 4 + (threadIdx.x >> 6));
    int lane = threadIdx.x & 63;
    if (v >= NN) return;
    int grp = lane >> 4;
    int sub = lane & 15;
    int j = grp * 64 + sub * 4;

    fv4 ww0 = *(const fv4*)(We + j);
    fv4 ww1 = *(const fv4*)(We + 256 + j);
    fv4 ww2 = *(const fv4*)(We + 512 + j);
    fv4 ww3 = *(const fv4*)(We + 768 + j);
    fv4 ww4 = *(const fv4*)(We + 1024 + j);
    fv4 atv = *(const fv4*)(att + j);
    fv4 xrv = __builtin_convertvector(
        *(const hv4*)(xlp + (size_t)v * RSTRIDE + 256 + j), fv4);
    float tmp = temp[0];
    const float L2E = 1.44269504088896340736f;

    float mxd = -INFINITY, dend = 0.f;
    fv4 acc = {0.f, 0.f, 0.f, 0.f};

    int beg = rowoff[v], end = rowoff[v + 1];
    int i = beg;
    for (; i + 4 <= end; i += 4) {
        int s[4]; float4 a[4]; float q[4]; fv4 xv[4]; float l[4];
#pragma unroll
        for (int u = 0; u < 4; ++u) {
            s[u] = srcp[i + u];
            a[u] = eap[i + u];
            q[u] = tmp * erec[i + u];
        }
#pragma unroll
        for (int u = 0; u < 4; ++u)
            xv[u] = __builtin_convertvector(
                *(const hv4*)(xlp + (size_t)s[u] * RSTRIDE + j), fv4);
#pragma unroll
        for (int u = 0; u < 4; ++u) {
            fv4 m = xv[u] + xrv;
            m = m + a[u].x * ww0; m = m + a[u].y * ww1; m = m + a[u].z * ww2;
            m = m + a[u].w * ww3; m = m + q[u] * ww4;
            m = __builtin_elementwise_max(m, m * 0.2f);
            fv4 p = m * atv;
            l[u] = (p[0] + p[1]) + (p[2] + p[3]);
        }
#pragma unroll
        for (int u = 0; u < 4; ++u) l[u] = red16(l[u]) * L2E;
        float nm = fmaxf(fmaxf(l[0], l[1]), fmaxf(l[2], l[3]));
        nm = fmaxf(nm, mxd);
        float sc = fexp2(mxd - nm);
        float e0 = fexp2(l[0] - nm);
        float e1 = fexp2(l[1] - nm);
        float e2 = fexp2(l[2] - nm);
        float e3 = fexp2(l[3] - nm);
        mxd = nm;
        dend = dend * sc + ((e0 + e1) + (e2 + e3));
        acc = acc * sc +
              ((xv[0] * e0 + xv[1] * e1) + (xv[2] * e2 + xv[3] * e3));
    }
    for (; i < end; ++i) {
        int s0 = srcp[i];
        float4 a0 = eap[i];
        float q0 = tmp * erec[i];
        fv4 x0 = __builtin_convertvector(
            *(const hv4*)(xlp + (size_t)s0 * RSTRIDE + j), fv4);
        fv4 m0 = x0 + xrv;
        m0 = m0 + a0.x * ww0; m0 = m0 + a0.y * ww1; m0 = m0 + a0.z * ww2;
        m0 = m0 + a0.w * ww3; m0 = m0 + q0 * ww4;
        m0 = __builtin_elementwise_max(m0, m0 * 0.2f);
        fv4 p0 = m0 * atv;
        float l0 = (p0[0] + p0[1]) + (p0[2] + p0[3]);
        l0 = red16(l0) * L2E;
        float nm = fmaxf(mxd, l0);
        float sc = fexp2(mxd - nm);
        float e0 = fexp2(l0 - nm);
        mxd = nm;
        dend = dend * sc + e0;
        acc = acc * sc + x0 * e0;
    }

    float inv = __builtin_amdgcn_rcpf(dend + 1e-16f);
    if (MODE <= 1) {
        fv4 bb = *(const fv4*)(bias + j);
        fv4 o = acc * inv + bb;
        float s  = (o[0] + o[1]) + (o[2] + o[3]);
        fv4 oq = o * o;
        float s2 = (oq[0] + oq[1]) + (oq[2] + oq[3]);
        s = red16(s);   s += __shfl_xor(s, 16, 64);  s += __shfl_xor(s, 32, 64);
        s2 = red16(s2); s2 += __shfl_xor(s2, 16, 64); s2 += __shfl_xor(s2, 32, 64);
        float mu = s * (1.f / 256.f);
        float var = s2 * (1.f / 256.f) - mu * mu;
        float rs = __builtin_amdgcn_rsqf(var + 1e-5f);
        fv4 lw = *(const fv4*)(lnw + j);
        fv4 lb = *(const fv4*)(lnb + j);
        fv4 rr;
        if (MODE == 0)
            rr = __builtin_convertvector(
                *(const hv4*)(residH + (size_t)v * RSTRIDE + j), fv4);
        else
            rr = *(const fv4*)(residF + (size_t)v * 256 + j);
        fv4 y = (o - mu) * rs * lw + lb + rr;
        y[0] = (y[0] > 0.f) ? y[0] : fexp2(y[0] * L2E) - 1.f;
        y[1] = (y[1] > 0.f) ? y[1] : fexp2(y[1] * L2E) - 1.f;
        y[2] = (y[2] > 0.f) ? y[2] : fexp2(y[2] * L2E) - 1.f;
        y[3] = (y[3] > 0.f) ? y[3] : fexp2(y[3] * L2E) - 1.f;
        if (MODE == 0)
            *(fv4*)(outF + (size_t)v * 256 + j) = y;
        // fused A-swizzle for the next layer's GEMM (K=256, KC=16)
        int kc = j >> 4, half = (j >> 3) & 1, off = j & 7;
        size_t idx = (((size_t)(v >> 5) * 16 + kc) * 64 + (v & 31) + 32 * half) * 8 + off;
        hv4 yh = __builtin_convertvector(y, hv4);
        *(hv4*)(aswOut + idx) = yh;
    } else {
        fv4 r = acc * inv;
        r[0] += __shfl_xor(r[0], 16, 64); r[0] += __shfl_xor(r[0], 32, 64);
        r[1] += __shfl_xor(r[1], 16, 64); r[1] += __shfl_xor(r[1], 32, 64);
        r[2] += __shfl_xor(r[2], 16, 64); r[2] += __shfl_xor(r[2], 32, 64);
        r[3] += __shfl_xor(r[3], 16, 64); r[3] += __shfl_xor(r[3], 32, 64);
        fv4 bb = *(const fv4*)(bias + sub * 4);
        fv4 o = r * 0.25f + bb;
        float s  = (o[0] + o[1]) + (o[2] + o[3]);
        fv4 oq = o * o;
        float s2 = (oq[0] + oq[1]) + (oq[2] + oq[3]);
        s = red16(s);
        s2 = red16(s2);
        float mu = s * (1.f / 64.f);
        float var = s2 * (1.f / 64.f) - mu * mu;
        float rs = __builtin_amdgcn_rsqf(var + 1e-5f);
        fv4 lw = *(const fv4*)(lnw + sub * 4);
        fv4 lb = *(const fv4*)(lnb + sub * 4);
        fv4 rr = __builtin_convertvector(
            *(const hv4*)(residH + (size_t)v * RSTRIDE + sub * 4), fv4);
        fv4 y = (o - mu) * rs * lw + lb + rr;
        if (grp == 0)
            *(fv4*)(outF + (size_t)v * 64 + sub * 4) = y;
    }
}

// ------------------------------------------------------------------
extern "C" void kernel_launch(void* const* d_in, const int* in_sizes, int n_in,
                              void* d_out, int out_size, void* d_ws, size_t ws_size,
                              hipStream_t stream)
{
    const float* x    = (const float*)d_in[0];
    const int*   eidx = (const int*)d_in[1];
    const float* ea   = (const float*)d_in[2];
    const int* src = eidx;
    const int* dst = eidx + EE;

    const float *Wl[3], *bl[3], *Wr[3], *br[3], *We[3], *att[3], *temp[3],
                *bias[3], *lnw[3], *lnb[3];
    for (int i = 0; i < 3; ++i) {
        int b = 3 + i * 10;
        Wl[i]   = (const float*)d_in[b + 0];
        bl[i]   = (const float*)d_in[b + 1];
        Wr[i]   = (const float*)d_in[b + 2];
        br[i]   = (const float*)d_in[b + 3];
        We[i]   = (const float*)d_in[b + 4];
        att[i]  = (const float*)d_in[b + 5];
        temp[i] = (const float*)d_in[b + 6];
        bias[i] = (const float*)d_in[b + 7];
        lnw[i]  = (const float*)d_in[b + 8];
        lnb[i]  = (const float*)d_in[b + 9];
    }
    const float* pw0 = (const float*)d_in[33];
    const float* pb0 = (const float*)d_in[34];
    const float* pw2 = (const float*)d_in[35];
    const float* pb2 = (const float*)d_in[36];

    // workspace carve-up
    char* w = (char*)d_ws;
    float* h     = (float*)w; w += (size_t)NN * 256 * 4;          // 51.2 MB
    char*  gbase = w;         w += (size_t)NN * 256 * 4;          // Asw region
    _Float16* xlr = (_Float16*)w; w += (size_t)NN * 768 * 2;      // 76.8 MB
    float4* eap  = (float4*)w; w += (size_t)EE * 16;
    float* erec  = (float*)w; w += (size_t)EE * 4;
    int* srcp    = (int*)w;   w += (size_t)EE * 4;
    int* rowoff  = (int*)w;   w += (size_t)(NN + 16) * 4;
    int* cursor  = (int*)w;   w += (size_t)NN * 4;
    int* part    = (int*)w;   w += 1024;
    w = (char*)(((uintptr_t)w + 255) & ~(uintptr_t)255);
    _Float16* catB0 = (_Float16*)w; w += 196608;   // 24 nt x  8 kc x 512 h
    _Float16* catB1 = (_Float16*)w; w += 262144;   // 16 nt x 16 kc
    _Float16* catB2 = (_Float16*)w; w += 294912;   // 18 nt x 16 kc
    float* cb0 = (float*)w; w += 768 * 4;
    float* cb1 = (float*)w; w += 512 * 4;
    float* cb2 = (float*)w; w += 576 * 4;
    _Float16* Asw = (_Float16*)gbase;              // 1568 tiles @ K=256 = 25.7 MB

    dim3 blk(256);
    dim3 grid_e((EE + 255) / 256);
    dim3 grid_nw((NN + 3) / 4);
    dim3 grid_nb(NB);
    const int RB = 196;   // 256-row GEMM blocks (196*8 = 1568 row tiles)

    // ---- CSR by dst (shared by all 3 layers) ----
    hipMemsetAsync(cursor, 0, (size_t)NN * 4, stream);
    hipLaunchKernelGGL(hist_kernel, grid_e, blk, 0, stream, dst, cursor);
    hipLaunchKernelGGL(scan_local, grid_nb, blk, 0, stream, cursor, rowoff, part);
    hipLaunchKernelGGL(scan_part, dim3(1), blk, 0, stream, part, rowoff);
    hipLaunchKernelGGL(scan_add, grid_nb, blk, 0, stream, rowoff, part, cursor);
    hipLaunchKernelGGL(scatter_kernel, grid_e, blk, 0, stream,
                       src, dst, ea, rowoff, cursor, srcp, eap, erec);

    // ---- all weight swizzles + bias concats, one dispatch ----
    hipLaunchKernelGGL(prep_weights, dim3(192), blk, 0, stream,
                       Wl[0], Wr[0], pw0, Wl[1], Wr[1], Wl[2], Wr[2], pw2,
                       catB0, catB1, catB2,
                       bl[0], br[0], pb0, bl[1], br[1], bl[2], br[2], pb2,
                       cb0, cb1, cb2);

    // ---- Layer 0: swizzle x, one GEMM -> [xl|xr|res] fp16 rows of 768 ----
    swizzleA<<<dim3(1568, 2), blk, 0, stream>>>(x, Asw, NN, 128);
    gemm_mfma<<<dim3(RB, 12), blk, 0, stream>>>(
        Asw, catB0, cb0, xlr, NN, 128, 768);
    fused_attn_ln<0, 768><<<grid_nw, blk, 0, stream>>>(
        rowoff, srcp, eap, erec, xlr, We[0], att[0], temp[0],
        bias[0], lnw[0], lnb[0], xlr + 512, nullptr, h, Asw);

    // ---- Layer 1: one GEMM -> [xl|xr] rows of 512; resid = h ----
    gemm_mfma<<<dim3(RB, 8), blk, 0, stream>>>(
        Asw, catB1, cb1, xlr, NN, 256, 512);
    fused_attn_ln<1, 512><<<grid_nw, blk, 0, stream>>>(
        rowoff, srcp, eap, erec, xlr, We[1], att[1], temp[1],
        bias[1], lnw[1], lnb[1], nullptr, h, nullptr, Asw);

    // ---- Layer 2: single GEMM -> [xl|xr|res64] rows of 576 (9 groups) ----
    gemm_mfma<<<dim3(RB, 9), blk, 0, stream>>>(
        Asw, catB2, cb2, xlr, NN, 256, 576);
    fused_attn_ln<2, 576><<<grid_nw, blk, 0, stream>>>(
        rowoff, srcp, eap, erec, xlr, We[2], att[2], temp[2],
        bias[2], lnw[2], lnb[2], xlr + 512, nullptr, (float*)d_out, nullptr);
}

// Round 10
// 635.393 us; speedup vs baseline: 1.0653x; 1.0653x over previous
//
#include <hip/hip_runtime.h>
#include <math.h>

#define NN 50000
#define EE 800000
#define NB 196   // ceil(NN/256)

typedef _Float16 half8 __attribute__((ext_vector_type(8)));
typedef _Float16 hv4  __attribute__((ext_vector_type(4)));
typedef _Float16 hv2  __attribute__((ext_vector_type(2)));
typedef float floatx16 __attribute__((ext_vector_type(16)));
typedef float fv4 __attribute__((ext_vector_type(4)));

__device__ __forceinline__ float fexp2(float x) { return __builtin_amdgcn_exp2f(x); }

// DPP row_ror all-reduce within 16-lane rows: rotations by 1,2,4,8.
template<int CTRL>
__device__ __forceinline__ float dppadd(float x) {
    int t = __builtin_amdgcn_update_dpp(0, __float_as_int(x), CTRL, 0xf, 0xf, false);
    return x + __int_as_float(t);
}
__device__ __forceinline__ float red16(float x) {
    x = dppadd<0x121>(x);   // row_ror:1
    x = dppadd<0x122>(x);   // row_ror:2
    x = dppadd<0x124>(x);   // row_ror:4
    x = dppadd<0x128>(x);   // row_ror:8
    return x;
}

// ------------------------------------------------------------------
// Swizzle A (fp32 row-major M x K) into 32x32x16 MFMA A-fragment order.
// Grid x covers all tiles the GEMM reads (zero-fills past M).
// ------------------------------------------------------------------
__global__ __launch_bounds__(256) void swizzleA(
    const float* __restrict__ A, _Float16* __restrict__ Asw, int M, int K)
{
    int wave = threadIdx.x >> 6, lane = threadIdx.x & 63;
    int tile = blockIdx.x;
    int kc = blockIdx.y * 4 + wave;
    int KC = K >> 4;
    if (kc >= KC) return;
    int row = tile * 32 + (lane & 31);
    int k0 = kc * 16 + (lane >> 5) * 8;
    float4 v0 = make_float4(0.f, 0.f, 0.f, 0.f);
    float4 v1 = make_float4(0.f, 0.f, 0.f, 0.f);
    if (row < M) {
        const float* p = A + (size_t)row * K + k0;
        v0 = *(const float4*)p;
        v1 = *(const float4*)(p + 4);
    }
    half8 o;
    o[0] = (_Float16)v0.x; o[1] = (_Float16)v0.y;
    o[2] = (_Float16)v0.z; o[3] = (_Float16)v0.w;
    o[4] = (_Float16)v1.x; o[5] = (_Float16)v1.y;
    o[6] = (_Float16)v1.z; o[7] = (_Float16)v1.w;
    *(half8*)(Asw + (((size_t)tile * KC + kc) * 64 + lane) * 8) = o;
}

// ------------------------------------------------------------------
// All weight swizzles + bias concats in ONE dispatch.
// Columns even/odd interleaved per 64-col group: tile 2g = even cols,
// tile 2g+1 = odd cols -> GEMM epilogue packs pairs into 4B stores.
// ------------------------------------------------------------------
__global__ __launch_bounds__(256) void prep_weights(
    const float* __restrict__ s0, const float* __restrict__ s1,
    const float* __restrict__ s2, const float* __restrict__ s3,
    const float* __restrict__ s4, const float* __restrict__ s5,
    const float* __restrict__ s6, const float* __restrict__ s7,
    _Float16* __restrict__ catB0, _Float16* __restrict__ catB1,
    _Float16* __restrict__ catB2,
    const float* __restrict__ bl0, const float* __restrict__ br0,
    const float* __restrict__ pb0, const float* __restrict__ bl1,
    const float* __restrict__ br1, const float* __restrict__ bl2,
    const float* __restrict__ br2, const float* __restrict__ pb2,
    float* __restrict__ cb0, float* __restrict__ cb1, float* __restrict__ cb2)
{
    int b = blockIdx.x;
    if (b >= 184) {
        int t = (b - 184) * 256 + threadIdx.x;   // 0..2047
        if (t < 768) {
            cb0[t] = (t < 256) ? bl0[t] : (t < 512) ? br0[t - 256] : pb0[t - 512];
        } else if (t < 1280) {
            int u = t - 768;
            cb1[u] = (u < 256) ? bl1[u] : br1[u - 256];
        } else if (t < 1856) {
            int u = t - 1280;
            cb2[u] = (u < 256) ? bl2[u] : (u < 512) ? br2[u - 256] : pb2[u - 512];
        }
        return;
    }
    int wave = threadIdx.x >> 6, lane = threadIdx.x & 63;
    int pair = b * 4 + wave;     // 0..735
    const int cum[9] = {0, 64, 128, 192, 320, 448, 576, 704, 736};
    int job = 0;
    while (pair >= cum[job + 1]) ++job;
    const float* srcs[8] = {s0, s1, s2, s3, s4, s5, s6, s7};
    const int KCs[8] = {8, 8, 8, 16, 16, 16, 16, 16};
    const int NCs[8] = {256, 256, 256, 256, 256, 256, 256, 64};
    const int ntb[8] = {0, 8, 16, 0, 8, 0, 8, 16};
    _Float16* dsts[8] = {catB0, catB0, catB0, catB1, catB1, catB2, catB2, catB2};
    int p = pair - cum[job];
    int KC = KCs[job], NC = NCs[job];
    int nt = p / KC, kc = p - nt * KC;
    int n = (nt >> 1) * 64 + ((lane & 31) * 2) + (nt & 1);
    int k0 = kc * 16 + (lane >> 5) * 8;
    const float* B = srcs[job];
    half8 o;
#pragma unroll
    for (int jj = 0; jj < 8; ++jj)
        o[jj] = (_Float16)B[(size_t)(k0 + jj) * NC + n];
    int ntG = ntb[job] + nt;
    *(half8*)(dsts[job] + (((size_t)ntG * KC + kc) * 64 + lane) * 8) = o;
}

// ------------------------------------------------------------------
// MFMA GEMM (round-8 structure): block = 128 rows x 128 cols, wave-pair
// per 64-col group (even/odd tile pair); epilogue packs (even,odd) into
// one 4B store. No LDS (B is L2-resident).
// ------------------------------------------------------------------
__global__ __launch_bounds__(256) void gemm_mfma(
    const _Float16* __restrict__ Asw, const _Float16* __restrict__ Bsw,
    const float* __restrict__ bias, _Float16* __restrict__ C,
    int M, int K, int NC)
{
    const int wave = threadIdx.x >> 6, lane = threadIdx.x & 63;
    const int KC = K >> 4;
    const int rt0 = blockIdx.x * 4 + (wave & 1) * 2;
    const int NG = NC >> 6;
    int g = blockIdx.y * 2 + (wave >> 1);
    if (g >= NG) g = NG - 1;      // duplicate work for odd group counts

    const half8* Ap0 = (const half8*)Asw + (size_t)rt0 * KC * 64 + lane;
    const half8* Ap1 = Ap0 + (size_t)KC * 64;
    const half8* Bp0 = (const half8*)Bsw + (size_t)(2 * g) * KC * 64 + lane;
    const half8* Bp1 = Bp0 + (size_t)KC * 64;

    floatx16 accE0 = {0.f}, accE1 = {0.f}, accO0 = {0.f}, accO1 = {0.f};

#pragma unroll 4
    for (int kc = 0; kc < KC; ++kc) {
        half8 a0 = Ap0[(size_t)kc * 64];
        half8 a1 = Ap1[(size_t)kc * 64];
        half8 b0 = Bp0[(size_t)kc * 64];
        half8 b1 = Bp1[(size_t)kc * 64];
        accE0 = __builtin_amdgcn_mfma_f32_32x32x16_f16(a0, b0, accE0, 0, 0, 0);
        accE1 = __builtin_amdgcn_mfma_f32_32x32x16_f16(a1, b0, accE1, 0, 0, 0);
        accO0 = __builtin_amdgcn_mfma_f32_32x32x16_f16(a0, b1, accO0, 0, 0, 0);
        accO1 = __builtin_amdgcn_mfma_f32_32x32x16_f16(a1, b1, accO1, 0, 0, 0);
    }

    const int nlane = lane & 31, hs = lane >> 5;
    int colb = g * 64 + nlane * 2;
    float be = bias[colb], bo = bias[colb + 1];
#pragma unroll
    for (int r = 0; r < 16; ++r) {
        int rowin = (r & 3) + 8 * (r >> 2) + 4 * hs;
        int row0 = rt0 * 32 + rowin;
        int row1 = row0 + 32;
        if (row0 < M) {
            hv2 pe;
            pe[0] = (_Float16)(accE0[r] + be);
            pe[1] = (_Float16)(accO0[r] + bo);
            *(hv2*)(C + (size_t)row0 * NC + colb) = pe;
        }
        if (row1 < M) {
            hv2 po;
            po[0] = (_Float16)(accE1[r] + be);
            po[1] = (_Float16)(accO1[r] + bo);
            *(hv2*)(C + (size_t)row1 * NC + colb) = po;
        }
    }
}

// ------------------------------------------------------------------
// CSR build: histogram -> two-level scan -> scatter
// ------------------------------------------------------------------
__global__ __launch_bounds__(256) void hist_kernel(const int* __restrict__ dst,
                                                   int* __restrict__ deg)
{
    int e = blockIdx.x * 256 + threadIdx.x;
    if (e < EE) atomicAdd(&deg[dst[e]], 1);
}

__global__ __launch_bounds__(256) void scan_local(const int* __restrict__ deg,
                                                  int* __restrict__ rowoff,
                                                  int* __restrict__ part)
{
    __shared__ int sd[256];
    int tid = threadIdx.x;
    int i = blockIdx.x * 256 + tid;
    int v = (i < NN) ? deg[i] : 0;
    sd[tid] = v;
    __syncthreads();
    for (int off = 1; off < 256; off <<= 1) {
        int t = (tid >= off) ? sd[tid - off] : 0;
        __syncthreads();
        sd[tid] += t;
        __syncthreads();
    }
    if (i < NN) rowoff[i] = sd[tid] - v;
    if (tid == 255) part[blockIdx.x] = sd[255];
}

__global__ __launch_bounds__(256) void scan_part(int* __restrict__ part,
                                                 int* __restrict__ rowoff)
{
    __shared__ int sd[256];
    int tid = threadIdx.x;
    int v = (tid < NB) ? part[tid] : 0;
    sd[tid] = v;
    __syncthreads();
    for (int off = 1; off < 256; off <<= 1) {
        int t = (tid >= off) ? sd[tid - off] : 0;
        __syncthreads();
        sd[tid] += t;
        __syncthreads();
    }
    if (tid < NB) part[tid] = sd[tid] - v;
    if (tid == 0) rowoff[NN] = EE;
}

__global__ __launch_bounds__(256) void scan_add(int* __restrict__ rowoff,
                                                const int* __restrict__ part,
                                                int* __restrict__ cursor)
{
    int i = blockIdx.x * 256 + threadIdx.x;
    if (i < NN) {
        rowoff[i] += part[blockIdx.x];
        cursor[i] = 0;
    }
}

__global__ __launch_bounds__(256) void scatter_kernel(
    const int* __restrict__ src, const int* __restrict__ dst,
    const float* __restrict__ ea, const int* __restrict__ rowoff,
    int* __restrict__ cursor, int* __restrict__ srcp,
    float4* __restrict__ eap, float* __restrict__ erec)
{
    int e = blockIdx.x * 256 + threadIdx.x;
    if (e < EE) {
        int d = dst[e];
        int pos = rowoff[d] + atomicAdd(&cursor[d], 1);
        srcp[pos] = src[e];
        const float* p = ea + (size_t)e * 5;
        eap[pos] = make_float4(p[0], p[1], p[2], p[3]);
        erec[pos] = 1.0f / fmaxf(p[3], 1e-6f);
    }
}

// ------------------------------------------------------------------
// Fused GATv2 + LayerNorm + residual (+ELU) + A-swizzle for next GEMM.
// One wave per node, edge loop unrolled x4. CSR metadata scalarized:
// beg/end/src indices forced into SGPRs so srcp/eap/erec become s_loads
// and gather address math is scalar.
// ------------------------------------------------------------------
template<int MODE, int RSTRIDE>
__global__ __launch_bounds__(256) void fused_attn_ln(
    const int* __restrict__ rowoff, const int* __restrict__ srcp,
    const float4* __restrict__ eap, const float* __restrict__ erec,
    const _Float16* __restrict__ xlp,
    const float* __restrict__ We, const float* __restrict__ att,
    const float* __restrict__ temp, const float* __restrict__ bias,
    const float* __restrict__ lnw, const float* __restrict__ lnb,
    const _Float16* __restrict__ residH, const float* __restrict__ residF,
    float* __restrict__ outF, _Float16* __restrict__ aswOut)
{
    int v = __builtin_amdgcn_readfirstlane(blockIdx.x * 4 + (threadIdx.x >> 6));
    int lane = threadIdx.x & 63;
    if (v >= NN) return;
    int grp = lane >> 4;
    int sub = lane & 15;
    int j = grp * 64 + sub * 4;

    fv4 ww0 = *(const fv4*)(We + j);
    fv4 ww1 = *(const fv4*)(We + 256 + j);
    fv4 ww2 = *(const fv4*)(We + 512 + j);
    fv4 ww3 = *(const fv4*)(We + 768 + j);
    fv4 ww4 = *(const fv4*)(We + 1024 + j);
    fv4 atv = *(const fv4*)(att + j);
    fv4 xrv = __builtin_convertvector(
        *(const hv4*)(xlp + (size_t)v * RSTRIDE + 256 + j), fv4);
    float tmp = temp[0];
    const float L2E = 1.44269504088896340736f;

    float mxd = -INFINITY, dend = 0.f;
    fv4 acc = {0.f, 0.f, 0.f, 0.f};

    int beg = __builtin_amdgcn_readfirstlane(rowoff[v]);
    int end = __builtin_amdgcn_readfirstlane(rowoff[v + 1]);
    int i = beg;
    for (; i + 4 <= end; i += 4) {
        int s[4]; float4 a[4]; float q[4]; fv4 xv[4]; float l[4];
#pragma unroll
        for (int u = 0; u < 4; ++u) {
            s[u] = __builtin_amdgcn_readfirstlane(srcp[i + u]);
            a[u] = eap[i + u];
            q[u] = tmp * erec[i + u];
        }
#pragma unroll
        for (int u = 0; u < 4; ++u)
            xv[u] = __builtin_convertvector(
                *(const hv4*)(xlp + (size_t)s[u] * RSTRIDE + j), fv4);
#pragma unroll
        for (int u = 0; u < 4; ++u) {
            fv4 m = xv[u] + xrv;
            m = m + a[u].x * ww0; m = m + a[u].y * ww1; m = m + a[u].z * ww2;
            m = m + a[u].w * ww3; m = m + q[u] * ww4;
            m = __builtin_elementwise_max(m, m * 0.2f);
            fv4 p = m * atv;
            l[u] = (p[0] + p[1]) + (p[2] + p[3]);
        }
#pragma unroll
        for (int u = 0; u < 4; ++u) l[u] = red16(l[u]) * L2E;
        float nm = fmaxf(fmaxf(l[0], l[1]), fmaxf(l[2], l[3]));
        nm = fmaxf(nm, mxd);
        float sc = fexp2(mxd - nm);
        float e0 = fexp2(l[0] - nm);
        float e1 = fexp2(l[1] - nm);
        float e2 = fexp2(l[2] - nm);
        float e3 = fexp2(l[3] - nm);
        mxd = nm;
        dend = dend * sc + ((e0 + e1) + (e2 + e3));
        acc = acc * sc +
              ((xv[0] * e0 + xv[1] * e1) + (xv[2] * e2 + xv[3] * e3));
    }
    for (; i < end; ++i) {
        int s0 = __builtin_amdgcn_readfirstlane(srcp[i]);
        float4 a0 = eap[i];
        float q0 = tmp * erec[i];
        fv4 x0 = __builtin_convertvector(
            *(const hv4*)(xlp + (size_t)s0 * RSTRIDE + j), fv4);
        fv4 m0 = x0 + xrv;
        m0 = m0 + a0.x * ww0; m0 = m0 + a0.y * ww1; m0 = m0 + a0.z * ww2;
        m0 = m0 + a0.w * ww3; m0 = m0 + q0 * ww4;
        m0 = __builtin_elementwise_max(m0, m0 * 0.2f);
        fv4 p0 = m0 * atv;
        float l0 = (p0[0] + p0[1]) + (p0[2] + p0[3]);
        l0 = red16(l0) * L2E;
        float nm = fmaxf(mxd, l0);
        float sc = fexp2(mxd - nm);
        float e0 = fexp2(l0 - nm);
        mxd = nm;
        dend = dend * sc + e0;
        acc = acc * sc + x0 * e0;
    }

    float inv = __builtin_amdgcn_rcpf(dend + 1e-16f);
    if (MODE <= 1) {
        fv4 bb = *(const fv4*)(bias + j);
        fv4 o = acc * inv + bb;
        float s  = (o[0] + o[1]) + (o[2] + o[3]);
        fv4 oq = o * o;
        float s2 = (oq[0] + oq[1]) + (oq[2] + oq[3]);
        s = red16(s);   s += __shfl_xor(s, 16, 64);  s += __shfl_xor(s, 32, 64);
        s2 = red16(s2); s2 += __shfl_xor(s2, 16, 64); s2 += __shfl_xor(s2, 32, 64);
        float mu = s * (1.f / 256.f);
        float var = s2 * (1.f / 256.f) - mu * mu;
        float rs = __builtin_amdgcn_rsqf(var + 1e-5f);
        fv4 lw = *(const fv4*)(lnw + j);
        fv4 lb = *(const fv4*)(lnb + j);
        fv4 rr;
        if (MODE == 0)
            rr = __builtin_convertvector(
                *(const hv4*)(residH + (size_t)v * RSTRIDE + j), fv4);
        else
            rr = *(const fv4*)(residF + (size_t)v * 256 + j);
        fv4 y = (o - mu) * rs * lw + lb + rr;
        y[0] = (y[0] > 0.f) ? y[0] : fexp2(y[0] * L2E) - 1.f;
        y[1] = (y[1] > 0.f) ? y[1] : fexp2(y[1] * L2E) - 1.f;
        y[2] = (y[2] > 0.f) ? y[2] : fexp2(y[2] * L2E) - 1.f;
        y[3] = (y[3] > 0.f) ? y[3] : fexp2(y[3] * L2E) - 1.f;
        if (MODE == 0)
            *(fv4*)(outF + (size_t)v * 256 + j) = y;
        // fused A-swizzle for the next layer's GEMM (K=256, KC=16)
        int kc = j >> 4, half = (j >> 3) & 1, off = j & 7;
        size_t idx = (((size_t)(v >> 5) * 16 + kc) * 64 + (v & 31) + 32 * half) * 8 + off;
        hv4 yh = __builtin_convertvector(y, hv4);
        *(hv4*)(aswOut + idx) = yh;
    } else {
        fv4 r = acc * inv;
        r[0] += __shfl_xor(r[0], 16, 64); r[0] += __shfl_xor(r[0], 32, 64);
        r[1] += __shfl_xor(r[1], 16, 64); r[1] += __shfl_xor(r[1], 32, 64);
        r[2] += __shfl_xor(r[2], 16, 64); r[2] += __shfl_xor(r[2], 32, 64);
        r[3] += __shfl_xor(r[3], 16, 64); r[3] += __shfl_xor(r[3], 32, 64);
        fv4 bb = *(const fv4*)(bias + sub * 4);
        fv4 o = r * 0.25f + bb;
        float s  = (o[0] + o[1]) + (o[2] + o[3]);
        fv4 oq = o * o;
        float s2 = (oq[0] + oq[1]) + (oq[2] + oq[3]);
        s = red16(s);
        s2 = red16(s2);
        float mu = s * (1.f / 64.f);
        float var = s2 * (1.f / 64.f) - mu * mu;
        float rs = __builtin_amdgcn_rsqf(var + 1e-5f);
        fv4 lw = *(const fv4*)(lnw + sub * 4);
        fv4 lb = *(const fv4*)(lnb + sub * 4);
        fv4 rr = __builtin_convertvector(
            *(const hv4*)(residH + (size_t)v * RSTRIDE + sub * 4), fv4);
        fv4 y = (o - mu) * rs * lw + lb + rr;
        if (grp == 0)
            *(fv4*)(outF + (size_t)v * 64 + sub * 4) = y;
    }
}

// ------------------------------------------------------------------
extern "C" void kernel_launch(void* const* d_in, const int* in_sizes, int n_in,
                              void* d_out, int out_size, void* d_ws, size_t ws_size,
                              hipStream_t stream)
{
    const float* x    = (const float*)d_in[0];
    const int*   eidx = (const int*)d_in[1];
    const float* ea   = (const float*)d_in[2];
    const int* src = eidx;
    const int* dst = eidx + EE;

    const float *Wl[3], *bl[3], *Wr[3], *br[3], *We[3], *att[3], *temp[3],
                *bias[3], *lnw[3], *lnb[3];
    for (int i = 0; i < 3; ++i) {
        int b = 3 + i * 10;
        Wl[i]   = (const float*)d_in[b + 0];
        bl[i]   = (const float*)d_in[b + 1];
        Wr[i]   = (const float*)d_in[b + 2];
        br[i]   = (const float*)d_in[b + 3];
        We[i]   = (const float*)d_in[b + 4];
        att[i]  = (const float*)d_in[b + 5];
        temp[i] = (const float*)d_in[b + 6];
        bias[i] = (const float*)d_in[b + 7];
        lnw[i]  = (const float*)d_in[b + 8];
        lnb[i]  = (const float*)d_in[b + 9];
    }
    const float* pw0 = (const float*)d_in[33];
    const float* pb0 = (const float*)d_in[34];
    const float* pw2 = (const float*)d_in[35];
    const float* pb2 = (const float*)d_in[36];

    // workspace carve-up
    char* w = (char*)d_ws;
    float* h     = (float*)w; w += (size_t)NN * 256 * 4;          // 51.2 MB
    char*  gbase = w;         w += (size_t)NN * 256 * 4;          // Asw region
    _Float16* xlr = (_Float16*)w; w += (size_t)NN * 768 * 2;      // 76.8 MB
    float4* eap  = (float4*)w; w += (size_t)EE * 16;
    float* erec  = (float*)w; w += (size_t)EE * 4;
    int* srcp    = (int*)w;   w += (size_t)EE * 4;
    int* rowoff  = (int*)w;   w += (size_t)(NN + 16) * 4;
    int* cursor  = (int*)w;   w += (size_t)NN * 4;
    int* part    = (int*)w;   w += 1024;
    w = (char*)(((uintptr_t)w + 255) & ~(uintptr_t)255);
    _Float16* catB0 = (_Float16*)w; w += 196608;   // 24 nt x  8 kc x 512 h
    _Float16* catB1 = (_Float16*)w; w += 262144;   // 16 nt x 16 kc
    _Float16* catB2 = (_Float16*)w; w += 294912;   // 18 nt x 16 kc
    float* cb0 = (float*)w; w += 768 * 4;
    float* cb1 = (float*)w; w += 512 * 4;
    float* cb2 = (float*)w; w += 576 * 4;
    _Float16* Asw = (_Float16*)gbase;              // 1564 tiles @ K=256 = 25.6 MB

    dim3 blk(256);
    dim3 grid_e((EE + 255) / 256);
    dim3 grid_nw((NN + 3) / 4);
    dim3 grid_nb(NB);
    const int MT = 391;   // ceil(50000/128) -> 1564 row tiles

    // ---- CSR by dst (shared by all 3 layers) ----
    hipMemsetAsync(cursor, 0, (size_t)NN * 4, stream);
    hipLaunchKernelGGL(hist_kernel, grid_e, blk, 0, stream, dst, cursor);
    hipLaunchKernelGGL(scan_local, grid_nb, blk, 0, stream, cursor, rowoff, part);
    hipLaunchKernelGGL(scan_part, dim3(1), blk, 0, stream, part, rowoff);
    hipLaunchKernelGGL(scan_add, grid_nb, blk, 0, stream, rowoff, part, cursor);
    hipLaunchKernelGGL(scatter_kernel, grid_e, blk, 0, stream,
                       src, dst, ea, rowoff, cursor, srcp, eap, erec);

    // ---- all weight swizzles + bias concats, one dispatch ----
    hipLaunchKernelGGL(prep_weights, dim3(192), blk, 0, stream,
                       Wl[0], Wr[0], pw0, Wl[1], Wr[1], Wl[2], Wr[2], pw2,
                       catB0, catB1, catB2,
                       bl[0], br[0], pb0, bl[1], br[1], bl[2], br[2], pb2,
                       cb0, cb1, cb2);

    // ---- Layer 0: swizzle x, one GEMM -> [xl|xr|res] fp16 rows of 768 ----
    swizzleA<<<dim3(1564, 2), blk, 0, stream>>>(x, Asw, NN, 128);
    gemm_mfma<<<dim3(MT, 6), blk, 0, stream>>>(
        Asw, catB0, cb0, xlr, NN, 128, 768);
    fused_attn_ln<0, 768><<<grid_nw, blk, 0, stream>>>(
        rowoff, srcp, eap, erec, xlr, We[0], att[0], temp[0],
        bias[0], lnw[0], lnb[0], xlr + 512, nullptr, h, Asw);

    // ---- Layer 1: one GEMM -> [xl|xr] rows of 512; resid = h ----
    gemm_mfma<<<dim3(MT, 4), blk, 0, stream>>>(
        Asw, catB1, cb1, xlr, NN, 256, 512);
    fused_attn_ln<1, 512><<<grid_nw, blk, 0, stream>>>(
        rowoff, srcp, eap, erec, xlr, We[1], att[1], temp[1],
        bias[1], lnw[1], lnb[1], nullptr, h, nullptr, Asw);

    // ---- Layer 2: single GEMM -> [xl|xr|res64] rows of 576 (9 groups) ----
    gemm_mfma<<<dim3(MT, 5), blk, 0, stream>>>(
        Asw, catB2, cb2, xlr, NN, 256, 576);
    fused_attn_ln<2, 576><<<grid_nw, blk, 0, stream>>>(
        rowoff, srcp, eap, erec, xlr, We[2], att[2], temp[2],
        bias[2], lnw[2], lnb[2], xlr + 512, nullptr, (float*)d_out, nullptr);
}